// Round 5
// baseline (424.005 us; speedup 1.0000x reference)
//
#include <hip/hip_runtime.h>
#include <hip/hip_bf16.h>
#include <hip/hip_fp16.h>

typedef _Float16 f16;
typedef _Float16 f16x2 __attribute__((ext_vector_type(2)));
typedef _Float16 f16x4 __attribute__((ext_vector_type(4)));
typedef _Float16 f16x8 __attribute__((ext_vector_type(8)));
typedef float f32x4 __attribute__((ext_vector_type(4)));

#define BN_EPS 1e-5f

// ---------------- kernel 1: graph start offsets from sorted segment_ids ----------------
__global__ void seg_starts_k(const int* __restrict__ seg, int N, int G, int* __restrict__ start) {
    int n = blockIdx.x * blockDim.x + threadIdx.x;
    if (n >= N) return;
    int s = seg[n];
    int p = (n == 0) ? -1 : seg[n - 1];
    for (int g = p + 1; g <= s; ++g) start[g] = n;
    if (n == N - 1) {
        for (int g = s + 1; g <= G; ++g) start[g] = N;
    }
}

// ---------------- kernel 2: weight prep (BN folding, fp16 transpose) ----------------
__global__ void prep_k(const float* __restrict__ W1, const float* __restrict__ b1,
                       const float* __restrict__ W2, const float* __restrict__ b2,
                       const float* __restrict__ W3, const float* __restrict__ b3,
                       const float* __restrict__ oW1, const float* __restrict__ ob1,
                       const float* __restrict__ g1, const float* __restrict__ be1,
                       const float* __restrict__ rm1, const float* __restrict__ rv1,
                       const float* __restrict__ g2, const float* __restrict__ be2,
                       const float* __restrict__ rm2, const float* __restrict__ rv2,
                       const float* __restrict__ g3, const float* __restrict__ be3,
                       const float* __restrict__ rm3, const float* __restrict__ rv3,
                       f16* __restrict__ Wt, float* __restrict__ bp) {
    int T = gridDim.x;
    int t = blockIdx.x, l = blockIdx.y;
    int o = threadIdx.x;  // 0..127
    __shared__ float s_sh[128], c_sh[128];

    const float *W, *b, *gg = nullptr, *be = nullptr, *rm = nullptr, *rv = nullptr;
    if (l == 0)      { W = W1;  b = b1; }
    else if (l == 1) { W = W2;  b = b2;  gg = g1; be = be1; rm = rm1; rv = rv1; }
    else if (l == 2) { W = W3;  b = b3;  gg = g2; be = be2; rm = rm2; rv = rv2; }
    else             { W = oW1; b = ob1; gg = g3; be = be3; rm = rm3; rv = rv3; }

    float s = 1.f, c = 0.f;
    if (gg) {
        float sv = gg[t * 128 + o] * rsqrtf(rv[t * 128 + o] + BN_EPS);
        s = sv;
        c = be[t * 128 + o] - rm[t * 128 + o] * sv;
    }
    s_sh[o] = s;
    c_sh[o] = c;
    __syncthreads();

    const float* Wsrc = W + (size_t)t * 128 * 128;
    f16* Wdst = Wt + (((size_t)l * T + t) * 128 + o) * 128;  // [l][t][o][i]
    float acc = b[t * 128 + o];
    for (int i = 0; i < 128; ++i) {
        float wv = Wsrc[i * 128 + o];
        Wdst[i] = (f16)(s_sh[i] * wv);
        acc += c_sh[i] * wv;
    }
    bp[((size_t)l * T + t) * 128 + o] = acc;
}

// ---------------- kernel 3: block-cooperative streaming pooling ----------------
// Block = 256 thr (4 waves) owns atoms [A0, A0+128).
//  1) stage 64KB feats slab -> f16 LDS (swizzled), 16 float4 loads/thread, deep MLP
//  2) w[a][t] for all 128 atoms: 8 weight-MFMA chains (w is graph-independent),
//     bounced through padded wls[128][20]
//  3) waves take graphs round-robin; masked pooling MFMAs from LDS only.
// Graphs cut by a 128-boundary write f32 partials to pt[boundary][side]; fixup_k sums.
__global__ __launch_bounds__(256) void pool2_k(const float* __restrict__ feats,
                                               const float* __restrict__ atom_w,
                                               const float* __restrict__ atom_b,
                                               const int* __restrict__ seg,
                                               const int* __restrict__ start,
                                               f16* __restrict__ mol,
                                               float* __restrict__ pt,
                                               int N, int G) {
    __shared__ f16 xs[128][128];   // 32KB, slot-swizzled
    __shared__ f16 wls[128][20];   // padded: banks spread across kg groups

    int b = blockIdx.x;
    int A0 = b * 128;
    int cnt = N - A0; if (cnt > 128) cnt = 128;
    int tid = threadIdx.x;
    int wave = tid >> 6, lane = tid & 63;
    int lr = lane & 15, kg = lane >> 4;

    // early scalar loads (latency)
    int segPrev = (A0 > 0) ? seg[A0 - 1] : -1;
    int segFirst = seg[A0];
    int segLast = seg[A0 + cnt - 1];

    // B-fragment for weight MFMA: atom_w[t=lr][k]
    f16x8 bfr[4];
    float ab = 0.f;
#pragma unroll
    for (int ks = 0; ks < 4; ++ks) {
        f16x8 v = {};
        if (lr < 12) {
            const float* s = atom_w + lr * 128 + ks * 32 + kg * 8;
#pragma unroll
            for (int j = 0; j < 8; ++j) v[j] = (f16)s[j];
        }
        bfr[ks] = v;
    }
    if (lr < 12) ab = atom_b[lr];

    // 1) stage slab
#pragma unroll
    for (int it = 0; it < 16; ++it) {
        int v = tid + it * 256;            // float4 index, 0..4095
        int r = v >> 5, q = v & 31;        // local atom, float4-in-row
        float4 u = make_float4(0.f, 0.f, 0.f, 0.f);
        if (r < cnt) u = *(const float4*)(feats + (size_t)A0 * 128 + (size_t)v * 4);
        f16x4 h;
        h[0] = (f16)u.x; h[1] = (f16)u.y; h[2] = (f16)u.z; h[3] = (f16)u.w;
        *(f16x4*)(&xs[r][(((q >> 1) ^ (r & 7)) << 3) + ((q & 1) << 2)]) = h;
    }
    __syncthreads();

    // 2) weight phase: wave handles tiles {wave, wave+4}
#pragma unroll
    for (int tt = 0; tt < 2; ++tt) {
        int tau = wave + tt * 4;
        f32x4 pa = {0.f, 0.f, 0.f, 0.f};
#pragma unroll
        for (int ks = 0; ks < 4; ++ks) {
            int row = tau * 16 + lr;
            f16x8 afr = *(const f16x8*)(&xs[row][((((ks << 2) + kg)) ^ (lr & 7)) << 3]);
            pa = __builtin_amdgcn_mfma_f32_16x16x32_f16(afr, bfr[ks], pa, 0, 0, 0);
        }
#pragma unroll
        for (int j = 0; j < 4; ++j) {
            float w = (lr < 12) ? 1.f / (1.f + __expf(-(pa[j] + ab))) : 0.f;
            wls[tau * 16 + (kg << 2) + j][lr] = (f16)w;
        }
    }
    __syncthreads();

    // 3) graph phase
    int gA = (A0 == 0) ? 0 : segPrev + 1;
    if (A0 > 0 && segFirst == segPrev) gA = segFirst;   // head-cut graph
    int gHi = (A0 + cnt >= N) ? (G - 1) : segLast;

    for (int g = gA + wave; g <= gHi; g += 4) {
        int s = start[g], e = start[g + 1];
        int lls = s - A0; if (lls < 0) lls = 0;
        int lle = e - A0; if (lle > cnt) lle = cnt;

        f32x4 acc[8];
#pragma unroll
        for (int nf = 0; nf < 8; ++nf) acc[nf] = (f32x4){0.f, 0.f, 0.f, 0.f};

        if (lls < lle) {
            int ta = lls >> 4, tb = (lle - 1) >> 4;
            for (int tau = ta; tau <= tb; ++tau) {
                // A-frag: w[task=lr][atom k=kg*4+j], masked to [lls,lle)
                f16x4 a2;
#pragma unroll
                for (int j = 0; j < 4; ++j) {
                    int la = tau * 16 + (kg << 2) + j;
                    f16 w = wls[la][lr];
                    a2[j] = (la >= lls && la < lle) ? w : (f16)0.f;
                }
#pragma unroll
                for (int nf = 0; nf < 8; ++nf) {
                    f16x4 b2;
#pragma unroll
                    for (int j = 0; j < 4; ++j) {
                        int la = tau * 16 + (kg << 2) + j;
                        int f = (nf << 4) + lr;
                        b2[j] = xs[la][(((f >> 3) ^ (la & 7)) << 3) + (f & 7)];
                    }
                    acc[nf] = __builtin_amdgcn_mfma_f32_16x16x16f16(a2, b2, acc[nf], 0, 0, 0);
                }
            }
        }

        bool tailcut = (e > A0 + cnt) && (A0 + cnt < N);
        bool headcut = (s < A0);
        if (tailcut) {
            float* d = pt + ((size_t)b * 2 + 0) * 1536;
            if (kg < 3) {
#pragma unroll
                for (int nf = 0; nf < 8; ++nf)
#pragma unroll
                    for (int j = 0; j < 4; ++j)
                        d[((kg << 2) + j) * 128 + (nf << 4) + lr] = acc[nf][j];
        } } else if (headcut) {
            float* d = pt + ((size_t)(b - 1) * 2 + 1) * 1536;
            if (kg < 3) {
#pragma unroll
                for (int nf = 0; nf < 8; ++nf)
#pragma unroll
                    for (int j = 0; j < 4; ++j)
                        d[((kg << 2) + j) * 128 + (nf << 4) + lr] = acc[nf][j];
        } } else {
            f16* d = mol + (size_t)g * 1536;
            if (kg < 3) {
#pragma unroll
                for (int nf = 0; nf < 8; ++nf)
#pragma unroll
                    for (int j = 0; j < 4; ++j)
                        d[((kg << 2) + j) * 128 + (nf << 4) + lr] = (f16)acc[nf][j];
        } }
    }
}

// ---------------- kernel 3b: boundary fixup ----------------
__global__ __launch_bounds__(256) void fixup_k(const int* __restrict__ seg,
                                               const float* __restrict__ pt,
                                               f16* __restrict__ mol, int nbd) {
    int wave = threadIdx.x >> 6, lane = threadIdx.x & 63;
    int bd = blockIdx.x * 4 + wave;
    if (bd >= nbd) return;
    int p = (bd + 1) * 128;
    int g0 = seg[p - 1], g1 = seg[p];
    if (g0 != g1) return;                  // boundary aligned: no cut graph
    const float* p0 = pt + (size_t)bd * 2 * 1536;
    const float* p1 = p0 + 1536;
    f16* d = mol + (size_t)g1 * 1536;
#pragma unroll
    for (int it = 0; it < 3; ++it) {
        int i = it * 512 + lane * 8;
        float4 a0 = *(const float4*)(p0 + i);
        float4 a1 = *(const float4*)(p0 + i + 4);
        float4 c0 = *(const float4*)(p1 + i);
        float4 c1 = *(const float4*)(p1 + i + 4);
        f16x8 h;
        h[0] = (f16)(a0.x + c0.x); h[1] = (f16)(a0.y + c0.y);
        h[2] = (f16)(a0.z + c0.z); h[3] = (f16)(a0.w + c0.w);
        h[4] = (f16)(a1.x + c1.x); h[5] = (f16)(a1.y + c1.y);
        h[6] = (f16)(a1.z + c1.z); h[7] = (f16)(a1.w + c1.w);
        *(f16x8*)(d + i) = h;
    }
}

// ---------------- kernel 4: fused 4-layer MLP + final dot, fp16 MFMA ----------------
// mol layout [g][t][f]. (unchanged from round 4)
__global__ __launch_bounds__(256, 2) void fc_k(const f16* __restrict__ mol,
                                               const f16* __restrict__ Wt,
                                               const float* __restrict__ bp,
                                               const float* __restrict__ oW2,
                                               const float* __restrict__ ob2,
                                               float* __restrict__ out, int G, int T) {
    __shared__ f16 A[2][64][128];
    __shared__ f16 B[128][128];

    int t = blockIdx.y;
    int g0 = blockIdx.x * 64;
    int tid = threadIdx.x;

    {
#pragma unroll
        for (int k = 0; k < 4; ++k) {
            int c = tid + k * 256;          // 0..1023
            int r = c >> 4, sl = c & 15;
            uint4 v = make_uint4(0u, 0u, 0u, 0u);
            if (g0 + r < G)
                v = *(const uint4*)(mol + ((size_t)(g0 + r) * T + t) * 128 + sl * 8);
            *(uint4*)(&A[0][r][(sl ^ (r & 7)) * 8]) = v;
        }
    }
    {
        const f16* src = Wt + ((size_t)0 * T + t) * 128 * 128;
#pragma unroll
        for (int k = 0; k < 8; ++k) {
            int c = tid + k * 256;          // 0..2047
            int r = c >> 4, sl = c & 15;
            uint4 v = *(const uint4*)(src + (size_t)r * 128 + sl * 8);
            *(uint4*)(&B[r][(sl ^ (r & 7)) * 8]) = v;
        }
    }
    __syncthreads();

    int wid = tid >> 6, lane = tid & 63;
    int lg = lane >> 4, lr = lane & 15;
    int m0 = wid * 16;
    int arow = m0 + lr;
    float pred[4] = {0.f, 0.f, 0.f, 0.f};
    int cur = 0;

    for (int l = 0; l < 4; ++l) {
        f16x8 afr[4];
#pragma unroll
        for (int ks = 0; ks < 4; ++ks) {
            int sl = (4 * ks + lg) ^ (arow & 7);
            afr[ks] = *(const f16x8*)(&A[cur][arow][sl * 8]);
        }
        const float* bias = bp + ((size_t)l * T + t) * 128;
#pragma unroll
        for (int nf = 0; nf < 8; ++nf) {
            int n = nf * 16 + lr;
            f32x4 acc = {0.f, 0.f, 0.f, 0.f};
#pragma unroll
            for (int ks = 0; ks < 4; ++ks) {
                int sl = (4 * ks + lg) ^ (n & 7);
                f16x8 bfr = *(const f16x8*)(&B[n][sl * 8]);
                acc = __builtin_amdgcn_mfma_f32_16x16x32_f16(afr[ks], bfr, acc, 0, 0, 0);
            }
            float bv = bias[n];
            if (l < 3) {
#pragma unroll
                for (int j = 0; j < 4; ++j) {
                    float y = acc[j] + bv;
                    y = y > 0.f ? y : 0.f;
                    int rr = m0 + 4 * lg + j;
                    A[cur ^ 1][rr][(((n >> 3) ^ (rr & 7)) << 3) + (n & 7)] = (f16)y;
                }
            } else {
                float w2 = oW2[t * 128 + n];
#pragma unroll
                for (int j = 0; j < 4; ++j) {
                    float z = acc[j] + bv;
                    z = z > 0.f ? z : 0.f;
                    pred[j] += z * w2;
                }
            }
        }
        __syncthreads();
        if (l < 3) {
            const f16* src = Wt + ((size_t)(l + 1) * T + t) * 128 * 128;
#pragma unroll
            for (int k = 0; k < 8; ++k) {
                int c = tid + k * 256;
                int r = c >> 4, sl = c & 15;
                uint4 v = *(const uint4*)(src + (size_t)r * 128 + sl * 8);
                *(uint4*)(&B[r][(sl ^ (r & 7)) * 8]) = v;
            }
            __syncthreads();
            cur ^= 1;
        }
    }

#pragma unroll
    for (int m = 1; m < 16; m <<= 1) {
#pragma unroll
        for (int j = 0; j < 4; ++j) pred[j] += __shfl_xor(pred[j], m, 64);
    }
    if (lr == 0) {
        float ob = ob2[t];
#pragma unroll
        for (int j = 0; j < 4; ++j) {
            int gg = g0 + m0 + 4 * lg + j;
            if (gg < G) out[(size_t)gg * T + t] = pred[j] + ob;
        }
    }
}

extern "C" void kernel_launch(void* const* d_in, const int* in_sizes, int n_in,
                              void* d_out, int out_size, void* d_ws, size_t ws_size,
                              hipStream_t stream) {
    const float* node_feats = (const float*)d_in[0];
    const int*   seg        = (const int*)d_in[1];
    const float* atom_w     = (const float*)d_in[3];
    const float* atom_b     = (const float*)d_in[4];
    const float* W1  = (const float*)d_in[5];
    const float* b1  = (const float*)d_in[6];
    const float* g1  = (const float*)d_in[7];
    const float* be1 = (const float*)d_in[8];
    const float* rm1 = (const float*)d_in[9];
    const float* rv1 = (const float*)d_in[10];
    const float* W2  = (const float*)d_in[11];
    const float* b2  = (const float*)d_in[12];
    const float* g2  = (const float*)d_in[13];
    const float* be2 = (const float*)d_in[14];
    const float* rm2 = (const float*)d_in[15];
    const float* rv2 = (const float*)d_in[16];
    const float* W3  = (const float*)d_in[17];
    const float* b3  = (const float*)d_in[18];
    const float* g3  = (const float*)d_in[19];
    const float* be3 = (const float*)d_in[20];
    const float* rm3 = (const float*)d_in[21];
    const float* rv3 = (const float*)d_in[22];
    const float* oW1 = (const float*)d_in[23];
    const float* ob1 = (const float*)d_in[24];
    const float* oW2 = (const float*)d_in[25];
    const float* ob2 = (const float*)d_in[26];

    int T = in_sizes[4];          // 12
    int F = in_sizes[3] / T;      // 128
    int N = in_sizes[0] / F;      // 1,000,000
    int G = out_size / T;         // 50,000
    int nb = (N + 127) / 128;     // pooling blocks
    int nbd = nb - 1;             // boundaries

    char* ws = (char*)d_ws;
    size_t off = 0;
    int* start = (int*)ws;
    off += (((size_t)(G + 1) * 4) + 255) & ~(size_t)255;
    f16* Wt = (f16*)(ws + off);
    off += (((size_t)4 * T * 128 * 128 * 2) + 255) & ~(size_t)255;
    float* bp = (float*)(ws + off);
    off += (((size_t)4 * T * 128 * 4) + 255) & ~(size_t)255;
    f16* mol = (f16*)(ws + off);
    off += (((size_t)G * 12 * 128 * 2) + 255) & ~(size_t)255;
    float* pt = (float*)(ws + off);

    seg_starts_k<<<(N + 255) / 256, 256, 0, stream>>>(seg, N, G, start);
    prep_k<<<dim3(T, 4), 128, 0, stream>>>(W1, b1, W2, b2, W3, b3, oW1, ob1,
                                           g1, be1, rm1, rv1,
                                           g2, be2, rm2, rv2,
                                           g3, be3, rm3, rv3, Wt, bp);
    pool2_k<<<nb, 256, 0, stream>>>(node_feats, atom_w, atom_b, seg, start, mol, pt, N, G);
    fixup_k<<<(nbd + 3) / 4, 256, 0, stream>>>(seg, pt, mol, nbd);
    fc_k<<<dim3((G + 63) / 64, T), 256, 0, stream>>>(mol, Wt, bp, oW2, ob2,
                                                     (float*)d_out, G, T);
}